// Round 1
// baseline (166.276 us; speedup 1.0000x reference)
//
#include <hip/hip_runtime.h>

using f4 = __attribute__((ext_vector_type(4))) float;

__device__ __forceinline__ float silu_f(float v) {
    return v * __builtin_amdgcn_rcpf(1.0f + __expf(-v));
}

// z_l = silu(emb1 @ Wz[l] + bz[l]) : (2,64,128) @ (128,64) -> z[l][b][n][k]
extern "C" __global__ void k_z(const float* __restrict__ emb1,
                               const float* __restrict__ Wz,
                               const float* __restrict__ bz,
                               float* __restrict__ z) {
    int tid = blockIdx.x * 256 + threadIdx.x;   // 24576 total
    int k = tid & 63;
    int n = (tid >> 6) & 63;
    int b = (tid >> 12) & 1;
    int l = tid >> 13;
    const float* er = emb1 + (b * 64 + n) * 128;
    const float* w  = Wz + l * 8192 + k;
    float acc = bz[l * 64 + k];
    #pragma unroll 8
    for (int c = 0; c < 128; ++c) acc = fmaf(er[c], w[c * 64], acc);
    z[tid] = silu_f(acc);
}

// e_l = ef @ Wef[l] : (8192,64) @ (64,64) -> e[l][row][k], row=(b*64+i)*64+j
extern "C" __global__ void k_e(const float* __restrict__ ef,
                               const float* __restrict__ Wef,
                               float* __restrict__ e) {
    int tid = blockIdx.x * 256 + threadIdx.x;   // 1572864 total
    int k = tid & 63;
    int row = (tid >> 6) & 8191;
    int l = tid >> 19;
    const float* efr = ef + row * 64;
    const float* w   = Wef + l * 4096 + k;
    float acc = 0.0f;
    #pragma unroll 8
    for (int c = 0; c < 64; ++c) acc = fmaf(efr[c], w[c * 64], acc);
    e[tid] = acc;
}

// Per (b,i,j): build X[k][c] (64x64), run 2-layer silu MLP + residual, store.
extern "C" __global__ void __launch_bounds__(256, 2)
k_main(const float* __restrict__ z, const float* __restrict__ e,
       const float* __restrict__ table, const float* __restrict__ Wm,
       const float* __restrict__ bm, float* __restrict__ out) {
    __shared__ float Wl[4096];       // current layer weights [c][ko]
    __shared__ float Xt[64][68];     // X transposed: Xt[c][k]
    __shared__ float Ht[64][68];     // H transposed: Ht[c][k]

    const int t   = threadIdx.x;
    const int bid = blockIdx.x;
    const int j = bid & 63;
    const int i = (bid >> 6) & 63;
    const int b = bid >> 12;

    // stage W0 (16KB, coalesced)
    #pragma unroll
    for (int p = 0; p < 4; ++p) {
        int idx = p * 1024 + t * 4;
        *(f4*)&Wl[idx] = *(const f4*)&Wm[idx];
    }

    const int r0 = (t >> 4) << 2;    // row (k) base of 4x4 tile
    const int c0 = (t & 15) << 2;    // col (c / ko) base of 4x4 tile

    const float* z0p = z + b * 4096;                               // [k*64+c]
    const float* z1p = z + 8192  + b * 4096 + i * 64;              // [c]
    const float* z2p = z + 16384 + b * 4096 + j * 64;              // [c]
    const float* e0p = e + (b * 64 + j) * 4096;                    // [k*64+c]
    const float* e1p = e + 524288  + (b * 64 + i) * 4096;          // [k*64+c]
    const float* e2p = e + 1048576 + ((b * 64 + i) * 64 + j) * 64; // [c]

    f4 z1v = *(const f4*)(z1p + c0);
    f4 z2v = *(const f4*)(z2p + c0);
    f4 e2v = *(const f4*)(e2p + c0);
    f4 pre = z1v * z2v * e2v;

    // build X tile, write transposed into LDS
    #pragma unroll
    for (int dr = 0; dr < 4; ++dr) {
        int kk = r0 + dr;
        int p = (i == j) ? 5 : (j == kk) ? 4 : (i == kk) ? 3 : 1;
        f4 z0v = *(const f4*)(z0p + kk * 64 + c0);
        f4 e0v = *(const f4*)(e0p + kk * 64 + c0);
        f4 e1v = *(const f4*)(e1p + kk * 64 + c0);
        f4 pv  = *(const f4*)(table + p * 64 + c0);
        f4 xv  = z0v * pre * e0v * e1v * pv;
        #pragma unroll
        for (int dc = 0; dc < 4; ++dc) Xt[c0 + dc][kk] = xv[dc];
    }
    __syncthreads();

    // ---- layer 1: H = silu(X @ W0 + b0) ----
    float acc[4][4];
    #pragma unroll
    for (int dr = 0; dr < 4; ++dr)
        #pragma unroll
        for (int dk = 0; dk < 4; ++dk) acc[dr][dk] = bm[c0 + dk];

    #pragma unroll 8
    for (int c = 0; c < 64; ++c) {
        f4 xa = *(const f4*)&Xt[c][r0];
        f4 wa = *(const f4*)&Wl[c * 64 + c0];
        #pragma unroll
        for (int dr = 0; dr < 4; ++dr)
            #pragma unroll
            for (int dk = 0; dk < 4; ++dk)
                acc[dr][dk] = fmaf(xa[dr], wa[dk], acc[dr][dk]);
    }
    float h[4][4];
    #pragma unroll
    for (int dr = 0; dr < 4; ++dr)
        #pragma unroll
        for (int dk = 0; dk < 4; ++dk) h[dr][dk] = silu_f(acc[dr][dk]);

    __syncthreads();   // everyone done reading Wl(=W0) and writing nothing

    // stage W1 over Wl; write H transposed
    #pragma unroll
    for (int p = 0; p < 4; ++p) {
        int idx = p * 1024 + t * 4;
        *(f4*)&Wl[idx] = *(const f4*)&Wm[4096 + idx];
    }
    #pragma unroll
    for (int dk = 0; dk < 4; ++dk)
        #pragma unroll
        for (int dr = 0; dr < 4; ++dr) Ht[c0 + dk][r0 + dr] = h[dr][dk];
    __syncthreads();

    // ---- layer 2: O = silu(H @ W1 + b1) + X ----
    float acc2[4][4];
    #pragma unroll
    for (int dr = 0; dr < 4; ++dr)
        #pragma unroll
        for (int dk = 0; dk < 4; ++dk) acc2[dr][dk] = bm[64 + c0 + dk];

    #pragma unroll 8
    for (int c = 0; c < 64; ++c) {
        f4 xa = *(const f4*)&Ht[c][r0];
        f4 wa = *(const f4*)&Wl[c * 64 + c0];
        #pragma unroll
        for (int dr = 0; dr < 4; ++dr)
            #pragma unroll
            for (int dk = 0; dk < 4; ++dk)
                acc2[dr][dk] = fmaf(xa[dr], wa[dk], acc2[dr][dk]);
    }

    float o[4][4];
    #pragma unroll
    for (int dk = 0; dk < 4; ++dk) {
        f4 xr = *(const f4*)&Xt[c0 + dk][r0];   // x[r0+dr][c0+dk]
        #pragma unroll
        for (int dr = 0; dr < 4; ++dr)
            o[dr][dk] = silu_f(acc2[dr][dk]) + xr[dr];
    }

    float* ob = out + (size_t)bid * 4096;
    #pragma unroll
    for (int dr = 0; dr < 4; ++dr) {
        f4 ov = { o[dr][0], o[dr][1], o[dr][2], o[dr][3] };
        *(f4*)(ob + (r0 + dr) * 64 + c0) = ov;
    }
}

extern "C" void kernel_launch(void* const* d_in, const int* in_sizes, int n_in,
                              void* d_out, int out_size, void* d_ws, size_t ws_size,
                              hipStream_t stream) {
    const float* emb1  = (const float*)d_in[0];
    const float* ef    = (const float*)d_in[1];
    const float* Wz    = (const float*)d_in[2];
    const float* bz    = (const float*)d_in[3];
    const float* Wef   = (const float*)d_in[4];
    const float* table = (const float*)d_in[5];
    const float* Wm    = (const float*)d_in[6];
    const float* bm    = (const float*)d_in[7];
    float* out = (float*)d_out;

    float* z = (float*)d_ws;          // 3*2*64*64      = 24576 floats
    float* e = z + 24576;             // 3*2*64*64*64   = 1572864 floats

    k_z  <<<96,   256, 0, stream>>>(emb1, Wz, bz, z);
    k_e  <<<6144, 256, 0, stream>>>(ef, Wef, e);
    k_main<<<8192, 256, 0, stream>>>(z, e, table, Wm, bm, out);
}

// Round 2
// 157.210 us; speedup vs baseline: 1.0577x; 1.0577x over previous
//
#include <hip/hip_runtime.h>

typedef __attribute__((ext_vector_type(4))) float f4;
typedef __attribute__((ext_vector_type(8))) short bf8;   // 8 x bf16 bits
typedef __attribute__((ext_vector_type(4))) float f32x4;

__device__ __forceinline__ float silu_f(float v) {
    return v * __builtin_amdgcn_rcpf(1.0f + __expf(-v));
}
__device__ __forceinline__ ushort f2bf(float f) {   // RNE f32->bf16
    unsigned u = __float_as_uint(f);
    u += 0x7fff + ((u >> 16) & 1);
    return (ushort)(u >> 16);
}

// z_l = silu(emb1 @ Wz[l] + bz[l]) : (2,64,128) @ (128,64) -> z[l][b][n][k]
extern "C" __global__ void k_z(const float* __restrict__ emb1,
                               const float* __restrict__ Wz,
                               const float* __restrict__ bz,
                               float* __restrict__ z) {
    int tid = blockIdx.x * 256 + threadIdx.x;   // 24576 total
    int k = tid & 63;
    int n = (tid >> 6) & 63;
    int b = (tid >> 12) & 1;
    int l = tid >> 13;
    const float* er = emb1 + (b * 64 + n) * 128;
    const float* w  = Wz + l * 8192 + k;
    float acc = bz[l * 64 + k];
    #pragma unroll 8
    for (int c = 0; c < 128; ++c) acc = fmaf(er[c], w[c * 64], acc);
    z[tid] = silu_f(acc);
}

// e_l = ef @ Wef[l] : (8192,64) @ (64,64) -> e[l][row][k]
extern "C" __global__ void k_e(const float* __restrict__ ef,
                               const float* __restrict__ Wef,
                               float* __restrict__ e) {
    int tid = blockIdx.x * 256 + threadIdx.x;   // 1572864 total
    int k = tid & 63;
    int row = (tid >> 6) & 8191;
    int l = tid >> 19;
    const float* efr = ef + row * 64;
    const float* w   = Wef + l * 4096 + k;
    float acc = 0.0f;
    #pragma unroll 8
    for (int c = 0; c < 64; ++c) acc = fmaf(efr[c], w[c * 64], acc);
    e[tid] = acc;
}

// WT[l][n][k] = bf16(Wm[l][k][n])  (B-operand, pre-transposed)
extern "C" __global__ void k_wt(const float* __restrict__ Wm,
                                ushort* __restrict__ WT) {
    int tid = blockIdx.x * 256 + threadIdx.x;   // 8192 total
    int l = tid >> 12;
    int n = (tid >> 6) & 63;
    int k = tid & 63;
    WT[tid] = f2bf(Wm[l * 4096 + k * 64 + n]);
}

// Per (b,i,j): build X (64x64), 2-layer silu MLP via MFMA, +residual, store.
extern "C" __global__ void __launch_bounds__(256, 4)
k_main(const float* __restrict__ z, const float* __restrict__ e,
       const float* __restrict__ table, const ushort* __restrict__ WT,
       const float* __restrict__ bm, float* __restrict__ out) {
    __shared__ ushort Xbf[4096];      // [64][64] bf16, XOR-swizzled rows (128B)
    __shared__ ushort Hbf[4096];      // same layout
    __shared__ float  XfT[64 * 68];   // f32 X transposed: [col][row], stride 68

    const int t   = threadIdx.x;
    const int bid = blockIdx.x;
    const int j = bid & 63, i = (bid >> 6) & 63, b = bid >> 12;

    // ---- build X: thread t -> row r, 16 cols starting at c0 ----
    {
        const int r  = t >> 2;
        const int c0 = (t & 3) << 4;
        const float* z0p = z + b * 4096 + r * 64 + c0;
        const float* z1p = z + 8192  + b * 4096 + i * 64 + c0;
        const float* z2p = z + 16384 + b * 4096 + j * 64 + c0;
        const float* e0p = e + ((b * 64 + j) * 64 + r) * 64 + c0;
        const float* e1p = e + 524288  + ((b * 64 + i) * 64 + r) * 64 + c0;
        const float* e2p = e + 1048576 + ((b * 64 + i) * 64 + j) * 64 + c0;
        const int p = (i == j) ? 5 : (j == r) ? 4 : (i == r) ? 3 : 1;
        const float* tp = table + p * 64 + c0;

        ushort xb[16];
        #pragma unroll
        for (int q = 0; q < 4; ++q) {
            f4 pre = *(const f4*)(z1p + 4 * q) * *(const f4*)(z2p + 4 * q)
                   * *(const f4*)(e2p + 4 * q);
            f4 xv = *(const f4*)(z0p + 4 * q) * pre
                  * *(const f4*)(e0p + 4 * q) * *(const f4*)(e1p + 4 * q)
                  * *(const f4*)(tp  + 4 * q);
            #pragma unroll
            for (int d = 0; d < 4; ++d) {
                int c = c0 + 4 * q + d;
                XfT[c * 68 + r] = xv[d];
                xb[4 * q + d] = f2bf(xv[d]);
            }
        }
        const int rx = (r & 7) << 4;
        char* rowp = (char*)Xbf + r * 128;
        #pragma unroll
        for (int s = 0; s < 2; ++s) {
            bf8 v;
            #pragma unroll
            for (int d = 0; d < 8; ++d) v[d] = (short)xb[8 * s + d];
            *(bf8*)(rowp + ((c0 * 2 + 16 * s) ^ rx)) = v;
        }
    }
    __syncthreads();

    const int l  = t & 63, w = t >> 6;
    const int lr = l & 15, lg = l >> 4;
    const int abyte = (w * 16 + lr) * 128;      // A-frag row base
    const int arx   = (lr & 7) << 4;            // row-XOR for that row

    // ---- layer 1: H = silu(X @ W0 + b0) ----
    bf8 bw[4][2];
    f32x4 acc[4];
    #pragma unroll
    for (int nt = 0; nt < 4; ++nt) {
        const ushort* wp = WT + (nt * 16 + lr) * 64 + lg * 8;
        bw[nt][0] = *(const bf8*)(wp);
        bw[nt][1] = *(const bf8*)(wp + 32);
        float bv = bm[nt * 16 + lr];
        acc[nt] = (f32x4){bv, bv, bv, bv};
    }
    bf8 a0 = *(const bf8*)((char*)Xbf + abyte + ((     lg * 16) ^ arx));
    bf8 a1 = *(const bf8*)((char*)Xbf + abyte + ((64 + lg * 16) ^ arx));
    #pragma unroll
    for (int nt = 0; nt < 4; ++nt) {
        acc[nt] = __builtin_amdgcn_mfma_f32_16x16x32_bf16(a0, bw[nt][0], acc[nt], 0, 0, 0);
        acc[nt] = __builtin_amdgcn_mfma_f32_16x16x32_bf16(a1, bw[nt][1], acc[nt], 0, 0, 0);
    }
    #pragma unroll
    for (int nt = 0; nt < 4; ++nt) {
        int col = nt * 16 + lr;
        #pragma unroll
        for (int rg = 0; rg < 4; ++rg) {
            int row = w * 16 + lg * 4 + rg;
            *(ushort*)((char*)Hbf + row * 128 + ((col * 2) ^ ((row & 7) << 4)))
                = f2bf(silu_f(acc[nt][rg]));
        }
    }
    __syncthreads();

    // ---- layer 2: O = silu(H @ W1 + b1) + X ----
    f32x4 acc2[4];
    #pragma unroll
    for (int nt = 0; nt < 4; ++nt) {
        const ushort* wp = WT + 4096 + (nt * 16 + lr) * 64 + lg * 8;
        bw[nt][0] = *(const bf8*)(wp);
        bw[nt][1] = *(const bf8*)(wp + 32);
        float bv = bm[64 + nt * 16 + lr];
        acc2[nt] = (f32x4){bv, bv, bv, bv};
    }
    bf8 h0 = *(const bf8*)((char*)Hbf + abyte + ((     lg * 16) ^ arx));
    bf8 h1 = *(const bf8*)((char*)Hbf + abyte + ((64 + lg * 16) ^ arx));
    #pragma unroll
    for (int nt = 0; nt < 4; ++nt) {
        acc2[nt] = __builtin_amdgcn_mfma_f32_16x16x32_bf16(h0, bw[nt][0], acc2[nt], 0, 0, 0);
        acc2[nt] = __builtin_amdgcn_mfma_f32_16x16x32_bf16(h1, bw[nt][1], acc2[nt], 0, 0, 0);
    }

    float* ob = out + (size_t)bid * 4096;
    #pragma unroll
    for (int nt = 0; nt < 4; ++nt) {
        int col = nt * 16 + lr;
        f32x4 xr = *(const f32x4*)&XfT[col * 68 + w * 16 + lg * 4];
        #pragma unroll
        for (int rg = 0; rg < 4; ++rg) {
            int row = w * 16 + lg * 4 + rg;
            ob[row * 64 + col] = silu_f(acc2[nt][rg]) + xr[rg];
        }
    }
}

extern "C" void kernel_launch(void* const* d_in, const int* in_sizes, int n_in,
                              void* d_out, int out_size, void* d_ws, size_t ws_size,
                              hipStream_t stream) {
    const float* emb1  = (const float*)d_in[0];
    const float* ef    = (const float*)d_in[1];
    const float* Wz    = (const float*)d_in[2];
    const float* bz    = (const float*)d_in[3];
    const float* Wef   = (const float*)d_in[4];
    const float* table = (const float*)d_in[5];
    const float* Wm    = (const float*)d_in[6];
    const float* bm    = (const float*)d_in[7];
    float* out = (float*)d_out;

    float*  zbuf = (float*)d_ws;          // 24576 f
    float*  ebuf = zbuf + 24576;          // 1572864 f
    ushort* WT   = (ushort*)(ebuf + 1572864);  // 8192 bf16

    k_z  <<<96,   256, 0, stream>>>(emb1, Wz, bz, zbuf);
    k_e  <<<6144, 256, 0, stream>>>(ef, Wef, ebuf);
    k_wt <<<32,   256, 0, stream>>>(Wm, WT);
    k_main<<<8192, 256, 0, stream>>>(zbuf, ebuf, table, WT, bm, out);
}

// Round 3
// 153.065 us; speedup vs baseline: 1.0863x; 1.0271x over previous
//
#include <hip/hip_runtime.h>

typedef __attribute__((ext_vector_type(4))) float f4;
typedef __attribute__((ext_vector_type(8))) short bf8;     // 8 x bf16 bits
typedef __attribute__((ext_vector_type(4))) float f32x4;
typedef __attribute__((ext_vector_type(4))) unsigned int u32x4;

__device__ __forceinline__ float silu_f(float v) {
    return v * __builtin_amdgcn_rcpf(1.0f + __expf(-v));
}
__device__ __forceinline__ ushort f2bf(float f) {   // RNE f32->bf16 (setup only)
    unsigned u = __float_as_uint(f);
    u += 0x7fff + ((u >> 16) & 1);
    return (ushort)(u >> 16);
}
__device__ __forceinline__ unsigned int cvtpk(float lo, float hi) {
    unsigned int r;
    asm("v_cvt_pk_bf16_f32 %0, %1, %2" : "=v"(r) : "v"(lo), "v"(hi));
    return r;   // D[15:0]=bf16(lo), D[31:16]=bf16(hi)
}

// fused: blocks 0..95 -> z_l = silu(emb1 @ Wz[l] + bz[l]); blocks 96..127 -> WT
extern "C" __global__ void k_zw(const float* __restrict__ emb1,
                                const float* __restrict__ Wz,
                                const float* __restrict__ bz,
                                const float* __restrict__ Wm,
                                float* __restrict__ z,
                                ushort* __restrict__ WT) {
    if (blockIdx.x < 96) {
        int tid = blockIdx.x * 256 + threadIdx.x;   // 24576
        int k = tid & 63;
        int n = (tid >> 6) & 63;
        int b = (tid >> 12) & 1;
        int l = tid >> 13;
        const float* er = emb1 + (b * 64 + n) * 128;
        const float* w  = Wz + l * 8192 + k;
        float acc = bz[l * 64 + k];
        #pragma unroll 8
        for (int c = 0; c < 128; ++c) acc = fmaf(er[c], w[c * 64], acc);
        z[tid] = silu_f(acc);
    } else {
        int tid = (blockIdx.x - 96) * 256 + threadIdx.x;  // 8192
        int l = tid >> 12, n = (tid >> 6) & 63, k = tid & 63;
        WT[tid] = f2bf(Wm[l * 4096 + k * 64 + n]);        // WT[l][n][k]=Wm[l][k][n]
    }
}

// e'_l = (ef @ Wef[l]) * z-factor : e'[l][row][k], row=(b*64+fi)*64+se
// l=0: *z0[b][se][k]   l=1: *z1[b][fi][k]   l=2: *z2[b][se][k]
extern "C" __global__ void k_e(const float* __restrict__ ef,
                               const float* __restrict__ Wef,
                               const float* __restrict__ z,
                               float* __restrict__ e) {
    int tid = blockIdx.x * 256 + threadIdx.x;   // 1572864
    int k = tid & 63;
    int row = (tid >> 6) & 8191;
    int l = tid >> 19;
    const float* efr = ef + row * 64;
    const float* w   = Wef + l * 4096 + k;
    float acc = 0.0f;
    #pragma unroll 8
    for (int c = 0; c < 64; ++c) acc = fmaf(efr[c], w[c * 64], acc);
    int b  = row >> 12;
    int mn = (l == 1) ? ((row >> 6) & 63) : (row & 63);
    acc *= z[l * 8192 + b * 4096 + mn * 64 + k];
    e[tid] = acc;
}

// Per block: (b, i, j-strip of 4). X = e0'*e1'*e2'*table; 2-layer silu MLP
// via MFMA; residual from bf16 X in LDS; coalesced-segment stores.
extern "C" __global__ void __launch_bounds__(256, 3)
k_main(const float* __restrict__ e, const float* __restrict__ table,
       const ushort* __restrict__ WT, const float* __restrict__ bm,
       float* __restrict__ out) {
    __shared__ ushort Xbf[2][4096];   // [64][64] bf16, XOR-swizzled 128B rows
    __shared__ ushort Hbf[4096];

    const int t   = threadIdx.x;
    const int bid = blockIdx.x;                 // 2048 blocks
    const int jq = bid & 15;
    const int i  = (bid >> 4) & 63;
    const int b  = bid >> 10;
    const int j0 = jq * 4;

    const int r  = t >> 2;                      // build row
    const int c0 = (t & 3) << 4;                // build col base (16 cols)

    const int l  = t & 63, w = t >> 6;          // frag ids
    const int lr = l & 15, lg = l >> 4;
    const int abyte = (w * 16 + lr) * 128;
    const int arx   = (lr & 7) << 4;

    // persistent: e1' slice (z1 pre-folded), layer-1 weights, biases
    const float* e1p = e + 524288 + ((b * 64 + i) * 64 + r) * 64 + c0;
    f4 pe[4];
    #pragma unroll
    for (int q = 0; q < 4; ++q) pe[q] = *(const f4*)(e1p + 4 * q);

    bf8 bw1[4][2];
    float bm0[4], bm1[4];
    #pragma unroll
    for (int nt = 0; nt < 4; ++nt) {
        const ushort* wp = WT + (nt * 16 + lr) * 64 + lg * 8;
        bw1[nt][0] = *(const bf8*)(wp);
        bw1[nt][1] = *(const bf8*)(wp + 32);
        bm0[nt] = bm[nt * 16 + lr];
        bm1[nt] = bm[64 + nt * 16 + lr];
    }

    const float* e0base = e + ((b * 64 + j0) * 64 + r) * 64 + c0;            // +4096/j
    const float* e2base = e + 1048576 + ((b * 64 + i) * 64 + j0) * 64 + c0;  // +64/j
    float* ob = out + (size_t)((b * 64 + i) * 64 + j0) * 4096;

    // prefetch tile 0 e0'
    f4 ce0[4];
    #pragma unroll
    for (int q = 0; q < 4; ++q) ce0[q] = *(const f4*)(e0base + 4 * q);

    #pragma unroll 1
    for (int jt = 0; jt < 4; ++jt) {
        const int jj = j0 + jt;
        ushort* xb = Xbf[jt & 1];

        // ---- phase A: build X tile, write bf16 swizzled ----
        {
            const float* e2p = e2base + jt * 64;
            const int p = (i == jj) ? 5 : (jj == r) ? 4 : (i == r) ? 3 : 1;
            const float* tp = table + p * 64 + c0;
            unsigned int xw[8];
            #pragma unroll
            for (int q = 0; q < 4; ++q) {
                f4 xv = pe[q] * ce0[q] * *(const f4*)(e2p + 4 * q)
                              * *(const f4*)(tp + 4 * q);
                xw[2 * q]     = cvtpk(xv[0], xv[1]);
                xw[2 * q + 1] = cvtpk(xv[2], xv[3]);
            }
            char* rowp = (char*)xb + r * 128;
            const int rx = (r & 7) << 4;
            u32x4 vlo = {xw[0], xw[1], xw[2], xw[3]};
            u32x4 vhi = {xw[4], xw[5], xw[6], xw[7]};
            *(u32x4*)(rowp + ((c0 * 2)      ^ rx)) = vlo;
            *(u32x4*)(rowp + ((c0 * 2 + 16) ^ rx)) = vhi;
        }
        __syncthreads();

        // ---- phase B: prefetch next tile; layer-1 GEMM ----
        if (jt < 3) {
            const float* ne0 = e0base + (jt + 1) * 4096;
            #pragma unroll
            for (int q = 0; q < 4; ++q) ce0[q] = *(const f4*)(ne0 + 4 * q);
        }
        // layer-2 weights: reload each tile (keep VGPR peak down; L1-hot)
        unsigned long long wta = (unsigned long long)(WT + 4096);
        asm("" : "+s"(wta));                    // block LICM hoist
        const ushort* wt2 = (const ushort*)wta;
        bf8 bw2[4][2];
        #pragma unroll
        for (int nt = 0; nt < 4; ++nt) {
            const ushort* wp = wt2 + (nt * 16 + lr) * 64 + lg * 8;
            bw2[nt][0] = *(const bf8*)(wp);
            bw2[nt][1] = *(const bf8*)(wp + 32);
        }

        bf8 a0 = *(const bf8*)((const char*)xb + abyte + ((     lg * 16) ^ arx));
        bf8 a1 = *(const bf8*)((const char*)xb + abyte + ((64 + lg * 16) ^ arx));
        f32x4 acc[4];
        #pragma unroll
        for (int nt = 0; nt < 4; ++nt) {
            acc[nt] = (f32x4){bm0[nt], bm0[nt], bm0[nt], bm0[nt]};
            acc[nt] = __builtin_amdgcn_mfma_f32_16x16x32_bf16(a0, bw1[nt][0], acc[nt], 0, 0, 0);
            acc[nt] = __builtin_amdgcn_mfma_f32_16x16x32_bf16(a1, bw1[nt][1], acc[nt], 0, 0, 0);
        }
        #pragma unroll
        for (int nt = 0; nt < 4; ++nt) {
            const int col = nt * 16 + lr;
            #pragma unroll
            for (int rg = 0; rg < 4; rg += 2) {
                const int row0 = w * 16 + lg * 4 + rg;
                const int row1 = row0 + 1;
                unsigned int pk = cvtpk(silu_f(acc[nt][rg]), silu_f(acc[nt][rg + 1]));
                Hbf[row0 * 64 + (col ^ ((row0 & 7) << 3))] = (ushort)pk;
                Hbf[row1 * 64 + (col ^ ((row1 & 7) << 3))] = (ushort)(pk >> 16);
            }
        }
        __syncthreads();

        // ---- phase C: layer-2 GEMM + residual + store ----
        bf8 h0 = *(const bf8*)((const char*)Hbf + abyte + ((     lg * 16) ^ arx));
        bf8 h1 = *(const bf8*)((const char*)Hbf + abyte + ((64 + lg * 16) ^ arx));
        f32x4 acc2[4];
        #pragma unroll
        for (int nt = 0; nt < 4; ++nt) {
            acc2[nt] = (f32x4){bm1[nt], bm1[nt], bm1[nt], bm1[nt]};
            acc2[nt] = __builtin_amdgcn_mfma_f32_16x16x32_bf16(h0, bw2[nt][0], acc2[nt], 0, 0, 0);
            acc2[nt] = __builtin_amdgcn_mfma_f32_16x16x32_bf16(h1, bw2[nt][1], acc2[nt], 0, 0, 0);
        }
        float* obj = ob + jt * 4096;
        #pragma unroll
        for (int nt = 0; nt < 4; ++nt) {
            const int col = nt * 16 + lr;
            #pragma unroll
            for (int rg = 0; rg < 4; ++rg) {
                const int row = w * 16 + lg * 4 + rg;
                float xres = __uint_as_float(
                    ((unsigned int)xb[row * 64 + (col ^ ((row & 7) << 3))]) << 16);
                obj[row * 64 + col] = silu_f(acc2[nt][rg]) + xres;
            }
        }
    }
}

extern "C" void kernel_launch(void* const* d_in, const int* in_sizes, int n_in,
                              void* d_out, int out_size, void* d_ws, size_t ws_size,
                              hipStream_t stream) {
    const float* emb1  = (const float*)d_in[0];
    const float* ef    = (const float*)d_in[1];
    const float* Wz    = (const float*)d_in[2];
    const float* bz    = (const float*)d_in[3];
    const float* Wef   = (const float*)d_in[4];
    const float* table = (const float*)d_in[5];
    const float* Wm    = (const float*)d_in[6];
    const float* bm    = (const float*)d_in[7];
    float* out = (float*)d_out;

    float*  zbuf = (float*)d_ws;                   // 24576 f
    float*  ebuf = zbuf + 24576;                   // 1572864 f
    ushort* WT   = (ushort*)(ebuf + 1572864);      // 8192 bf16

    k_zw  <<<128,  256, 0, stream>>>(emb1, Wz, bz, Wm, zbuf, WT);
    k_e   <<<6144, 256, 0, stream>>>(ef, Wef, zbuf, ebuf);
    k_main<<<2048, 256, 0, stream>>>(ebuf, table, WT, bm, out);
}

// Round 5
// 81.684 us; speedup vs baseline: 2.0356x; 1.8739x over previous
//
#include <hip/hip_runtime.h>

typedef __attribute__((ext_vector_type(4))) float f4;
typedef __attribute__((ext_vector_type(8))) short bf8;     // 8 x bf16 bits
typedef __attribute__((ext_vector_type(4))) float f32x4;
typedef __attribute__((ext_vector_type(2))) unsigned int u32x2;
typedef __attribute__((ext_vector_type(4))) unsigned int u32x4;

__device__ __forceinline__ float silu_f(float v) {
    return v * __builtin_amdgcn_rcpf(1.0f + __expf(-v));
}
__device__ __forceinline__ ushort f2bf(float f) {   // RNE f32->bf16 (setup only)
    unsigned u = __float_as_uint(f);
    u += 0x7fff + ((u >> 16) & 1);
    return (ushort)(u >> 16);
}
__device__ __forceinline__ unsigned cvtpk(float lo, float hi) {
    unsigned r;
    asm("v_cvt_pk_bf16_f32 %0, %1, %2" : "=v"(r) : "v"(lo), "v"(hi));
    return r;   // D[15:0]=bf16(lo), D[31:16]=bf16(hi)
}

// fused: blocks 0..95 -> z_l = silu(emb1 @ Wz[l] + bz[l]); blocks 96..127 -> WT
extern "C" __global__ void k_zw(const float* __restrict__ emb1,
                                const float* __restrict__ Wz,
                                const float* __restrict__ bz,
                                const float* __restrict__ Wm,
                                float* __restrict__ z,
                                ushort* __restrict__ WT) {
    if (blockIdx.x < 96) {
        int tid = blockIdx.x * 256 + threadIdx.x;   // 24576
        int k = tid & 63;
        int n = (tid >> 6) & 63;
        int b = (tid >> 12) & 1;
        int l = tid >> 13;
        const float* er = emb1 + (b * 64 + n) * 128;
        const float* w  = Wz + l * 8192 + k;
        float acc = bz[l * 64 + k];
        #pragma unroll 8
        for (int c = 0; c < 128; ++c) acc = fmaf(er[c], w[c * 64], acc);
        z[tid] = silu_f(acc);
    } else {
        int tid = (blockIdx.x - 96) * 256 + threadIdx.x;  // 8192
        int l = tid >> 12, n = (tid >> 6) & 63, k = tid & 63;
        WT[tid] = f2bf(Wm[l * 4096 + k * 64 + n]);        // WT[l][n][k]=Wm[l][k][n]
    }
}

// e'_l = (ef @ Wef[l]) * z-factor ; 4 outputs (k0..k0+3) per thread
extern "C" __global__ void k_e(const float* __restrict__ ef,
                               const float* __restrict__ Wef,
                               const float* __restrict__ z,
                               float* __restrict__ e) {
    int tid = blockIdx.x * 256 + threadIdx.x;   // 393216
    int k0  = (tid & 15) * 4;
    int row = (tid >> 4) & 8191;
    int l   = tid >> 17;
    const float* efr = ef + row * 64;
    const float* w   = Wef + l * 4096 + k0;
    f4 acc = {0.f, 0.f, 0.f, 0.f};
    #pragma unroll
    for (int c4 = 0; c4 < 16; ++c4) {
        f4 ev = *(const f4*)(efr + c4 * 4);
        #pragma unroll
        for (int q = 0; q < 4; ++q)
            acc += ev[q] * *(const f4*)(w + (c4 * 4 + q) * 64);
    }
    int b  = row >> 12;
    int mn = (l == 1) ? ((row >> 6) & 63) : (row & 63);
    acc *= *(const f4*)(z + l * 8192 + b * 4096 + mn * 64 + k0);
    *(f4*)(e + l * 524288 + row * 64 + k0) = acc;
}

// Per block: (b, i, j-strip of 4). Swapped-operand MFMA: lane holds 4
// consecutive output cols of one row -> dwordx4 stores, b64 residual reads.
extern "C" __global__ void __launch_bounds__(256, 4)
k_main(const float* __restrict__ e, const float* __restrict__ table,
       const ushort* __restrict__ WT, const float* __restrict__ bm,
       float* __restrict__ out) {
    __shared__ ushort Wl[8192];       // both layers, 128B rows, XOR-swizzled
    __shared__ ushort Xb[2][4096];    // X bf16, double-buffered
    __shared__ ushort Hb[4096];

    const int t   = threadIdx.x;
    const int bid = blockIdx.x;                 // 2048 blocks
    const int jq = bid & 15;
    const int i  = (bid >> 4) & 63;
    const int b  = bid >> 10;
    const int j0 = jq * 4;

    // stage BOTH weight layers swizzled into LDS: 1024 x 16B chunks
    // (round-4 bug: p<2 staged only layer 1 -> phase C read uninit LDS -> NaN)
    #pragma unroll
    for (int p = 0; p < 4; ++p) {
        int g   = p * 256 + t;                  // 1024 chunks
        int row = g >> 3;                       // 128 rows x 128B
        int cb  = (g & 7) * 16;
        u32x4 v = *(const u32x4*)(WT + g * 8);
        *(u32x4*)((char*)Wl + row * 128 + (cb ^ ((row & 7) << 4))) = v;
    }

    // build-role ids
    const int r  = t >> 2;
    const int c0 = (t & 3) << 4;
    // frag-role ids
    const int ln = t & 63, w = t >> 6;
    const int lr = ln & 15, lg = ln >> 4;
    const int abyte = (w * 16 + lr) * 128;
    const int arx   = (lr & 7) << 4;

    // persistent: e1'(i,r,:) * pat[1]
    const float* e1p = e + 524288 + ((b * 64 + i) * 64 + r) * 64 + c0;
    const float* p1  = table + 64 + c0;
    f4 pe1t[4];
    #pragma unroll
    for (int q = 0; q < 4; ++q)
        pe1t[q] = *(const f4*)(e1p + 4 * q) * *(const f4*)(p1 + 4 * q);

    const float* e0base = e + ((b * 64 + j0) * 64 + r) * 64 + c0;            // +4096/j
    const float* e2base = e + 1048576 + ((b * 64 + i) * 64 + j0) * 64 + c0;  // +64/j
    float* ob = out + (size_t)((b * 64 + i) * 64 + j0) * 4096;

    f4 ce0[4];
    #pragma unroll
    for (int q = 0; q < 4; ++q) ce0[q] = *(const f4*)(e0base + 4 * q);

    #pragma unroll 1
    for (int jt = 0; jt < 4; ++jt) {
        const int jj = j0 + jt;
        ushort* xb = Xb[jt & 1];

        // ---- phase A: build X tile (bf16, swizzled) ----
        {
            const float* e2p = e2base + jt * 64;
            f4 xv[4];
            bool slow = (i == jj) || (r == jj) || (r == i);
            if (slow) {
                int p = (i == jj) ? 5 : (jj == r) ? 4 : 3;
                const float* pp = table + p * 64 + c0;
                #pragma unroll
                for (int q = 0; q < 4; ++q)
                    xv[q] = *(const f4*)(e1p + 4 * q) * *(const f4*)(pp + 4 * q)
                          * *(const f4*)(e2p + 4 * q) * ce0[q];
            } else {
                #pragma unroll
                for (int q = 0; q < 4; ++q)
                    xv[q] = pe1t[q] * *(const f4*)(e2p + 4 * q) * ce0[q];
            }
            unsigned xw[8];
            #pragma unroll
            for (int q = 0; q < 4; ++q) {
                xw[2 * q]     = cvtpk(xv[q][0], xv[q][1]);
                xw[2 * q + 1] = cvtpk(xv[q][2], xv[q][3]);
            }
            char* rowp = (char*)xb + r * 128;
            const int rx = (r & 7) << 4;
            u32x4 vlo = {xw[0], xw[1], xw[2], xw[3]};
            u32x4 vhi = {xw[4], xw[5], xw[6], xw[7]};
            *(u32x4*)(rowp + ((c0 * 2)      ^ rx)) = vlo;
            *(u32x4*)(rowp + ((c0 * 2 + 16) ^ rx)) = vhi;
        }
        __syncthreads();

        // ---- phase B: GEMM1 swapped (D = W0^T · X^T) ----
        f4 ce0n[4];
        if (jt < 3) {
            const float* ne0 = e0base + (jt + 1) * 4096;
            #pragma unroll
            for (int q = 0; q < 4; ++q) ce0n[q] = *(const f4*)(ne0 + 4 * q);
        }
        bf8 a0 = *(const bf8*)((const char*)xb + abyte + ((     lg * 16) ^ arx));
        bf8 a1 = *(const bf8*)((const char*)xb + abyte + ((64 + lg * 16) ^ arx));
        #pragma unroll
        for (int nt = 0; nt < 4; ++nt) {
            const char* wb = (const char*)Wl + (nt * 16 + lr) * 128;
            bf8 b0 = *(const bf8*)(wb + ((     lg * 16) ^ arx));
            bf8 b1 = *(const bf8*)(wb + ((64 + lg * 16) ^ arx));
            f32x4 acc = *(const f4*)(bm + nt * 16 + lg * 4);   // bias as C-init
            acc = __builtin_amdgcn_mfma_f32_16x16x32_bf16(b0, a0, acc, 0, 0, 0);
            acc = __builtin_amdgcn_mfma_f32_16x16x32_bf16(b1, a1, acc, 0, 0, 0);
            unsigned pk0 = cvtpk(silu_f(acc[0]), silu_f(acc[1]));
            unsigned pk1 = cvtpk(silu_f(acc[2]), silu_f(acc[3]));
            u32x2 hv = {pk0, pk1};
            *(u32x2*)((char*)Hb + abyte + ((nt * 32 + lg * 8) ^ arx)) = hv;
        }
        __syncthreads();

        // ---- phase C: GEMM2 swapped + residual + dwordx4 store ----
        bf8 h0 = *(const bf8*)((const char*)Hb + abyte + ((     lg * 16) ^ arx));
        bf8 h1 = *(const bf8*)((const char*)Hb + abyte + ((64 + lg * 16) ^ arx));
        float* op = ob + (size_t)jt * 4096 + (w * 16 + lr) * 64 + lg * 4;
        #pragma unroll
        for (int nt = 0; nt < 4; ++nt) {
            const char* wb = (const char*)Wl + (64 + nt * 16 + lr) * 128;
            bf8 b0 = *(const bf8*)(wb + ((     lg * 16) ^ arx));
            bf8 b1 = *(const bf8*)(wb + ((64 + lg * 16) ^ arx));
            f32x4 acc = *(const f4*)(bm + 64 + nt * 16 + lg * 4);
            acc = __builtin_amdgcn_mfma_f32_16x16x32_bf16(b0, h0, acc, 0, 0, 0);
            acc = __builtin_amdgcn_mfma_f32_16x16x32_bf16(b1, h1, acc, 0, 0, 0);
            u32x2 rr = *(const u32x2*)((const char*)xb + abyte +
                                       ((nt * 32 + lg * 8) ^ arx));
            f4 ov;
            ov[0] = silu_f(acc[0]) + __uint_as_float(rr[0] << 16);
            ov[1] = silu_f(acc[1]) + __uint_as_float(rr[0] & 0xffff0000u);
            ov[2] = silu_f(acc[2]) + __uint_as_float(rr[1] << 16);
            ov[3] = silu_f(acc[3]) + __uint_as_float(rr[1] & 0xffff0000u);
            *(f4*)(op + nt * 16) = ov;
        }
        if (jt < 3) {
            #pragma unroll
            for (int q = 0; q < 4; ++q) ce0[q] = ce0n[q];
        }
    }
}

extern "C" void kernel_launch(void* const* d_in, const int* in_sizes, int n_in,
                              void* d_out, int out_size, void* d_ws, size_t ws_size,
                              hipStream_t stream) {
    const float* emb1  = (const float*)d_in[0];
    const float* ef    = (const float*)d_in[1];
    const float* Wz    = (const float*)d_in[2];
    const float* bz    = (const float*)d_in[3];
    const float* Wef   = (const float*)d_in[4];
    const float* table = (const float*)d_in[5];
    const float* Wm    = (const float*)d_in[6];
    const float* bm    = (const float*)d_in[7];
    float* out = (float*)d_out;

    float*  zbuf = (float*)d_ws;                   // 24576 f
    float*  ebuf = zbuf + 24576;                   // 1572864 f
    ushort* WT   = (ushort*)(ebuf + 1572864);      // 8192 bf16

    k_zw  <<<128,  256, 0, stream>>>(emb1, Wz, bz, Wm, zbuf, WT);
    k_e   <<<1536, 256, 0, stream>>>(ef, Wef, zbuf, ebuf);
    k_main<<<2048, 256, 0, stream>>>(ebuf, table, WT, bm, out);
}